// Round 6
// baseline (258.018 us; speedup 1.0000x reference)
//
#include <hip/hip_runtime.h>
#include <math.h>

#define BB 32
#define GG 15
#define KK 2048
#define NB 480               // B*G blocks; co-resident (launch_bounds(256,2) -> >=512 slots)
#define N1F 983040.0f
#define EPS 1e-5f

typedef _Float16 half8 __attribute__((ext_vector_type(8)));
typedef float f32x4 __attribute__((ext_vector_type(4)));

// ---- zeroed ws region (hipMemsetAsync each launch), float offsets ----
#define ZW_SREL  0      // 6 (+2 pad) global central 2nd moments (atomicAdd)
#define ZW_BN1S  8      // 64  sum h2   (atomicAdd from 480 blocks)
#define ZW_BN1Q  72     // 64  sumsq h2
#define ZW_S2AS  136    // 128 stage2 layer1 stats
#define ZW_S2AQ  264    // 128
#define ZW_S2BS  392    // 128 stage2 layer2
#define ZW_S2BQ  520    // 128
#define ZW_S3AS  648    // 256 stage3 layer1
#define ZW_S3AQ  904    // 256
#define ZW_S3BS  1160   // 256 stage3 layer2
#define ZW_S3BQ  1416   // 256
#define ZW_CNT   1672   // 8 ints: [0]=p1 [1]=p2 [2..5]=tail A..D
#define ZW_N     1680   // memset bytes = 6720
// ---- non-zeroed (atomicExch-written, agent-aload-read) ----
#define WS_CENT  1680                 // [480][4]
#define WS_MAXV  (WS_CENT + NB*4)     // [480][64]
#define WS_MINV  (WS_MAXV + NB*64)    // [480][64]

// ---- LDS map (floats, 7456 = 29824 B) ----
// phase 1-2: xls[6144]@0 | red arrays @6144/6400/6656/6912 | bcast[9]@7168
// tail alias: f2s@0(1005) h2a@1008(1920) h2b@2928(1920) f3s@4848(655)
//   h3a@5504(1280) sA@6784 tA@6848 c2ls@6912(15) c3ls@6928(3) centls@6932(45)
#define SMEMF 7456

__device__ const int SIDX[15] = {0,1,8, 2,4,6, 3,5,7, 9,11,13, 10,12,14};
__device__ const int INV[15]  = {0,1,3,6,4,7,5,8,2,9,12,10,13,11,14};

__device__ __forceinline__ float wave_sum(float v){
    for (int off = 32; off; off >>= 1) v += __shfl_down(v, off, 64);
    return v;
}
__device__ __forceinline__ float aloadf(const float* p){
    return __hip_atomic_load(p, __ATOMIC_RELAXED, __HIP_MEMORY_SCOPE_AGENT);
}
__device__ __forceinline__ int aloadi(const int* p){
    return __hip_atomic_load(p, __ATOMIC_RELAXED, __HIP_MEMORY_SCOPE_AGENT);
}
// drain this wave's outstanding VMEM (writes reach coherence point) before flagging
__device__ __forceinline__ void fence_vm(){
    asm volatile("" ::: "memory");
    __builtin_amdgcn_s_waitcnt(0x0F70);   // vmcnt(0)
    asm volatile("" ::: "memory");
}
// counter barrier: single poller, then block-sync
template<int SLP>
__device__ __forceinline__ void wait_counter(int* cnt, int target){
    if (threadIdx.x == 0) {
        int g = 0;
        while (aloadi(cnt) < target && ++g < 8000000)
            __builtin_amdgcn_s_sleep(SLP);
    }
    __syncthreads();
}

__global__ void __launch_bounds__(256, 2) mega(
        const float* __restrict__ x,
        const float* __restrict__ w00, const float* __restrict__ g00, const float* __restrict__ b00,
        const float* __restrict__ w01, const float* __restrict__ g01, const float* __restrict__ b01,
        const float* __restrict__ w10, const float* __restrict__ g10, const float* __restrict__ b10,
        const float* __restrict__ w11, const float* __restrict__ g11, const float* __restrict__ b11,
        const float* __restrict__ w20, const float* __restrict__ g20, const float* __restrict__ b20,
        const float* __restrict__ w21, const float* __restrict__ g21, const float* __restrict__ b21,
        float* __restrict__ ws, float* __restrict__ out) {
    __shared__ __align__(16) float smemf[SMEMF];
    float* xls  = smemf;
    float* redM = smemf + 6144; float* redN = smemf + 6400;
    float* redS = smemf + 6656; float* redQ = smemf + 6912;
    float* bcast= smemf + 7168;
    int* wsi = (int*)ws;
    int* cnt = wsi + ZW_CNT;

    int bid = blockIdx.x, tid = threadIdx.x;
    int b_ = bid / GG, g_ = bid % GG;
    int wv = tid >> 6, lane = tid & 63, l15 = lane & 15, quad = lane >> 4;

    // ================= phase 1: x -> LDS; centroid + 3x3 moments ===============
    {
        const float4* xp4 = (const float4*)(x + (size_t)bid * KK * 3);
        float4* xls4 = (float4*)xls;
        #pragma unroll
        for (int i = 0; i < 6; i++) xls4[i*256 + tid] = xp4[i*256 + tid];
        __syncthreads();
        float m[9] = {0,0,0,0,0,0,0,0,0};
        float a[24];
        const float* bp = &xls[tid*24];
        #pragma unroll
        for (int i = 0; i < 6; i++)
            *reinterpret_cast<float4*>(&a[i*4]) = *reinterpret_cast<const float4*>(&bp[i*4]);
        #pragma unroll
        for (int p = 0; p < 8; p++) {
            float ax=a[p*3], ay=a[p*3+1], az=a[p*3+2];
            m[0]+=ax; m[1]+=ay; m[2]+=az;
            m[3]=fmaf(ax,ax,m[3]); m[4]=fmaf(ay,ay,m[4]); m[5]=fmaf(az,az,m[5]);
            m[6]=fmaf(ax,ay,m[6]); m[7]=fmaf(ax,az,m[7]); m[8]=fmaf(ay,az,m[8]);
        }
        #pragma unroll
        for (int q = 0; q < 9; q++) {
            float v = wave_sum(m[q]);
            if (lane == 0) redM[q*4 + wv] = v;
        }
        __syncthreads();
        if (tid == 0) {
            float t[9];
            #pragma unroll
            for (int q = 0; q < 9; q++) t[q] = redM[q*4]+redM[q*4+1]+redM[q*4+2]+redM[q*4+3];
            float c0 = t[0]/KK, c1 = t[1]/KK, c2 = t[2]/KK;
            bcast[0]=c0; bcast[1]=c1; bcast[2]=c2;
            out[8192 + b_*(67*GG) + 0*GG + g_] = c0;
            out[8192 + b_*(67*GG) + 1*GG + g_] = c1;
            out[8192 + b_*(67*GG) + 2*GG + g_] = c2;
            atomicExch(&ws[WS_CENT + bid*4 + 0], c0);
            atomicExch(&ws[WS_CENT + bid*4 + 1], c1);
            atomicExch(&ws[WS_CENT + bid*4 + 2], c2);
            atomicAdd(&ws[ZW_SREL+0], t[3] - KK*c0*c0);
            atomicAdd(&ws[ZW_SREL+1], t[4] - KK*c1*c1);
            atomicAdd(&ws[ZW_SREL+2], t[5] - KK*c2*c2);
            atomicAdd(&ws[ZW_SREL+3], t[6] - KK*c0*c1);
            atomicAdd(&ws[ZW_SREL+4], t[7] - KK*c0*c2);
            atomicAdd(&ws[ZW_SREL+5], t[8] - KK*c1*c2);
            fence_vm();
            atomicAdd(&cnt[0], 1);
        }
    }
    wait_counter<4>(&cnt[0], NB);             // grid barrier 1 (single counter)
    if (tid < 6) bcast[3+tid] = aloadf(&ws[ZW_SREL+tid]) / N1F;
    __syncthreads();

    float c0 = bcast[0], c1 = bcast[1], c2v = bcast[2];
    float S00=bcast[3], S11=bcast[4], S22=bcast[5], S01=bcast[6], S02=bcast[7], S12=bcast[8];

    // ================= phase 2: barrier-free MFMA over 2048 k ==================
    float wa0[8], wa1[8], wa2[8], ba[8], wb0[8], wb1[8], wb2[8], bb[8];
    #pragma unroll
    for (int j = 0; j < 8; j++) {
        int cA = quad*8 + j;
        float u0=w00[cA*3+0], u1=w00[cA*3+1], u2=w00[cA*3+2];
        float var = u0*u0*S00 + u1*u1*S11 + u2*u2*S22
                  + 2.f*(u0*u1*S01 + u0*u2*S02 + u1*u2*S12);
        float a1 = g00[cA]*rsqrtf(var + EPS);
        wa0[j]=a1*u0; wa1[j]=a1*u1; wa2[j]=a1*u2; ba[j]=b00[cA];
        int cB = cA + 32;
        float v0=w00[cB*3+0], v1=w00[cB*3+1], v2=w00[cB*3+2];
        float varB = v0*v0*S00 + v1*v1*S11 + v2*v2*S22
                   + 2.f*(v0*v1*S01 + v0*v2*S02 + v1*v2*S12);
        float a1B = g00[cB]*rsqrtf(varB + EPS);
        wb0[j]=a1B*v0; wb1[j]=a1B*v1; wb2[j]=a1B*v2; bb[j]=b00[cB];
    }
    half8 afA[4], afB[4];
    #pragma unroll
    for (int t = 0; t < 4; t++)
        #pragma unroll
        for (int j = 0; j < 8; j++) {
            afA[t][j] = (_Float16)w01[(t*16 + l15)*64 + quad*8 + j];
            afB[t][j] = (_Float16)w01[(t*16 + l15)*64 + 32 + quad*8 + j];
        }
    float mx[16], mn[16], sm[16], sq[16];
    #pragma unroll
    for (int s = 0; s < 16; s++) { mx[s]=-1e30f; mn[s]=1e30f; sm[s]=0.f; sq[s]=0.f; }

    for (int it = 0; it < 32; it++) {
        int k = it*64 + wv*16 + l15;
        float r0 = xls[k*3+0]-c0, r1 = xls[k*3+1]-c1, r2 = xls[k*3+2]-c2v;
        half8 bf0, bf1;
        #pragma unroll
        for (int j = 0; j < 8; j++) {
            float pA = fmaf(wa0[j],r0, fmaf(wa1[j],r1, fmaf(wa2[j],r2, ba[j])));
            bf0[j] = (_Float16)fmaxf(pA, 0.f);
            float pB = fmaf(wb0[j],r0, fmaf(wb1[j],r1, fmaf(wb2[j],r2, bb[j])));
            bf1[j] = (_Float16)fmaxf(pB, 0.f);
        }
        #pragma unroll
        for (int t = 0; t < 4; t++) {
            f32x4 acc = {0.f,0.f,0.f,0.f};
            acc = __builtin_amdgcn_mfma_f32_16x16x32_f16(afA[t], bf0, acc, 0, 0, 0);
            acc = __builtin_amdgcn_mfma_f32_16x16x32_f16(afB[t], bf1, acc, 0, 0, 0);
            #pragma unroll
            for (int r = 0; r < 4; r++) {
                float h = acc[r];  // o = t*16 + quad*4 + r
                int s = t*4 + r;
                mx[s]=fmaxf(mx[s],h); mn[s]=fminf(mn[s],h);
                sm[s]+=h;             sq[s]=fmaf(h,h,sq[s]);
            }
        }
    }
    #pragma unroll
    for (int m = 1; m < 16; m <<= 1) {
        #pragma unroll
        for (int s = 0; s < 16; s++) {
            mx[s] = fmaxf(mx[s], __shfl_xor(mx[s], m, 64));
            mn[s] = fminf(mn[s], __shfl_xor(mn[s], m, 64));
            sm[s] += __shfl_xor(sm[s], m, 64);
            sq[s] += __shfl_xor(sq[s], m, 64);
        }
    }
    __syncthreads();   // xls dead; red arrays for cross-wave combine
    if (l15 == 0) {
        #pragma unroll
        for (int t = 0; t < 4; t++)
            #pragma unroll
            for (int r = 0; r < 4; r++) {
                int o = t*16 + quad*4 + r;
                redM[wv*64+o]=mx[t*4+r]; redN[wv*64+o]=mn[t*4+r];
                redS[wv*64+o]=sm[t*4+r]; redQ[wv*64+o]=sq[t*4+r];
            }
    }
    __syncthreads();
    if (tid < 64) {
        float M=-1e30f, N=1e30f, S=0.f, Q=0.f;
        #pragma unroll
        for (int w = 0; w < 4; w++) {
            M = fmaxf(M, redM[w*64+tid]); N = fminf(N, redN[w*64+tid]);
            S += redS[w*64+tid];          Q += redQ[w*64+tid];
        }
        atomicExch(&ws[WS_MAXV + bid*64 + tid], M);
        atomicExch(&ws[WS_MINV + bid*64 + tid], N);
        atomicAdd(&ws[ZW_BN1S + tid], S);
        atomicAdd(&ws[ZW_BN1Q + tid], Q);
        fence_vm();
    }
    __syncthreads();
    if (tid == 0) atomicAdd(&cnt[1], 1);

    if (bid >= BB) return;          // 448 blocks done; 32 tail blocks continue

    // ================= tail: stages 2+3, one block per batch b=bid =============
    wait_counter<4>(&cnt[1], NB);   // grid barrier 2

    float* f2s = smemf;        float* h2a = smemf + 1008;
    float* h2b = smemf + 2928; float* f3s = smemf + 4848;
    float* h3a = smemf + 5504;
    float* sA  = smemf + 6784; float* tA  = smemf + 6848;
    float* c2ls= smemf + 6912; float* c3ls= smemf + 6928;
    float* centls = smemf + 6932;   // [15][3]
    int b = bid;

    // ---- phase 0: BN1 stats (2 aloads/thread); centroids; c2/c3; lf1; feats2 ----
    {
        if (tid < 64) {
            float SM = aloadf(&ws[ZW_BN1S + tid]);
            float SQ = aloadf(&ws[ZW_BN1Q + tid]);
            float mean = SM / N1F;
            float var  = SQ / N1F - mean*mean;
            float s1 = g01[tid]*rsqrtf(var + EPS);
            sA[tid] = s1; tA[tid] = b01[tid] - mean*s1;
        } else if (tid < 109) {
            int t2 = tid - 64, g = t2/3, i = t2%3;
            centls[g*3+i] = aloadf(&ws[WS_CENT + (b*GG + g)*4 + i]);
        }
        __syncthreads();
        if (tid < 15) {
            int s = tid/3, i = tid%3;
            float acc = 0.f;
            for (int j = 0; j < 3; j++) acc += centls[SIDX[s*3+j]*3 + i];
            c2ls[tid] = acc * (1.f/3.f);
        }
        __syncthreads();
        if (tid < 3) {
            float a = 0.f;
            for (int s = 0; s < 5; s++) a += c2ls[s*3+tid];
            c3ls[tid] = a * 0.2f;
        }
        if (tid < 45) {
            int p = tid/3, i = tid%3;
            f2s[p*67 + i] = centls[SIDX[p]*3 + i] - c2ls[(p/3)*3 + i];
        }
        for (int idx = tid; idx < 960; idx += 256) {
            int g = idx >> 6, o2 = idx & 63, bg2 = b*GG + g;
            float s1 = sA[o2], t1 = tA[o2];
            float mxv = aloadf(&ws[WS_MAXV + bg2*64 + o2]);
            float mnv = aloadf(&ws[WS_MINV + bg2*64 + o2]);
            float val = fmaxf(fmaf(s1, (s1 >= 0.f) ? mxv : mnv, t1), 0.f);
            out[8192 + b*(67*GG) + (3+o2)*GG + g] = val;
            f2s[INV[g]*67 + 3 + o2] = val;
        }
        __syncthreads();
    }

    int o = tid & 127, ph = tid >> 7;

    // ---- phase A: h2a = w10 @ f2 + global stats ----
    {
        float accp[8] = {0,0,0,0,0,0,0,0};
        for (int c = 0; c < 67; c++) {
            float wv_ = w10[o*67 + c];
            #pragma unroll
            for (int pi = 0; pi < 8; pi++) {
                int p = ph + 2*pi;
                if (p < 15) accp[pi] = fmaf(wv_, f2s[p*67+c], accp[pi]);
            }
        }
        float smv=0.f, sqv=0.f;
        #pragma unroll
        for (int pi = 0; pi < 8; pi++) {
            int p = ph + 2*pi;
            if (p < 15) { float a=accp[pi]; h2a[p*128+o]=a; smv+=a; sqv=fmaf(a,a,sqv); }
        }
        atomicAdd(&ws[ZW_S2AS + o], smv);
        atomicAdd(&ws[ZW_S2AQ + o], sqv);
        fence_vm();
        __syncthreads();
        if (tid == 0) atomicAdd(&cnt[2], 1);
    }
    wait_counter<2>(&cnt[2], BB);

    // ---- phase B: BN2a + h2b = w11 @ v + stats ----
    {
        float mean = aloadf(&ws[ZW_S2AS + o]) / 480.f;
        float var  = aloadf(&ws[ZW_S2AQ + o]) / 480.f - mean*mean;
        float s2 = g10[o]*rsqrtf(var+EPS), t2v = b10[o] - mean*s2;
        for (int p = ph; p < 15; p += 2)
            h2a[p*128+o] = fmaxf(fmaf(s2, h2a[p*128+o], t2v), 0.f);
        __syncthreads();
        float accp[8] = {0,0,0,0,0,0,0,0};
        for (int i = 0; i < 128; i++) {
            float wv_ = w11[o*128 + i];
            #pragma unroll
            for (int pi = 0; pi < 8; pi++) {
                int p = ph + 2*pi;
                if (p < 15) accp[pi] = fmaf(wv_, h2a[p*128+i], accp[pi]);
            }
        }
        float smv=0.f, sqv=0.f;
        #pragma unroll
        for (int pi = 0; pi < 8; pi++) {
            int p = ph + 2*pi;
            if (p < 15) { float a=accp[pi]; h2b[p*128+o]=a; smv+=a; sqv=fmaf(a,a,sqv); }
        }
        atomicAdd(&ws[ZW_S2BS + o], smv);
        atomicAdd(&ws[ZW_S2BQ + o], sqv);
        fence_vm();
        __syncthreads();
        if (tid == 0) atomicAdd(&cnt[3], 1);
    }
    wait_counter<2>(&cnt[3], BB);

    // ---- phase C: lf2 = max_j relu(BN(h2b)); feats3; h3a = w20 @ f3; stats ----
    {
        float mean = aloadf(&ws[ZW_S2BS + o]) / 480.f;
        float var  = aloadf(&ws[ZW_S2BQ + o]) / 480.f - mean*mean;
        float s3 = g11[o]*rsqrtf(var+EPS), t3v = b11[o] - mean*s3;
        if (ph == 0) {
            for (int s5 = 0; s5 < 5; s5++) {
                float m = -1e30f;
                #pragma unroll
                for (int j = 0; j < 3; j++)
                    m = fmaxf(m, fmaxf(fmaf(s3, h2b[(s5*3+j)*128+o], t3v), 0.f));
                f3s[s5*131 + 3 + o] = m;
            }
        }
        if (tid < 15) f3s[(tid/3)*131 + tid%3] = c2ls[tid] - c3ls[tid%3];
        __syncthreads();
        float acc5[5] = {0,0,0,0,0};
        for (int c = 0; c < 131; c++) {
            float wv_ = w20[tid*131 + c];
            #pragma unroll
            for (int p = 0; p < 5; p++) acc5[p] = fmaf(wv_, f3s[p*131+c], acc5[p]);
        }
        float smv=0.f, sqv=0.f;
        #pragma unroll
        for (int p = 0; p < 5; p++) { float a=acc5[p]; h3a[p*256+tid]=a; smv+=a; sqv=fmaf(a,a,sqv); }
        atomicAdd(&ws[ZW_S3AS + tid], smv);
        atomicAdd(&ws[ZW_S3AQ + tid], sqv);
        fence_vm();
        __syncthreads();
        if (tid == 0) atomicAdd(&cnt[4], 1);
    }
    wait_counter<2>(&cnt[4], BB);

    // ---- phase D: BN3a + h3b (registers) = w21 @ v + stats ----
    float acc5[5] = {0,0,0,0,0};
    {
        float mean = aloadf(&ws[ZW_S3AS + tid]) / 160.f;
        float var  = aloadf(&ws[ZW_S3AQ + tid]) / 160.f - mean*mean;
        float s4 = g20[tid]*rsqrtf(var+EPS), t4v = b20[tid] - mean*s4;
        #pragma unroll
        for (int p = 0; p < 5; p++)
            h3a[p*256+tid] = fmaxf(fmaf(s4, h3a[p*256+tid], t4v), 0.f);
        __syncthreads();
        for (int i = 0; i < 256; i++) {
            float wv_ = w21[tid*256 + i];
            #pragma unroll
            for (int p = 0; p < 5; p++) acc5[p] = fmaf(wv_, h3a[p*256+i], acc5[p]);
        }
        float smv=0.f, sqv=0.f;
        #pragma unroll
        for (int p = 0; p < 5; p++) { smv += acc5[p]; sqv = fmaf(acc5[p], acc5[p], sqv); }
        atomicAdd(&ws[ZW_S3BS + tid], smv);
        atomicAdd(&ws[ZW_S3BQ + tid], sqv);
        fence_vm();
        __syncthreads();
        if (tid == 0) atomicAdd(&cnt[5], 1);
    }
    wait_counter<2>(&cnt[5], BB);

    // ---- phase E: gf = max_p relu(BN(h3b)) ----
    {
        float mean = aloadf(&ws[ZW_S3BS + tid]) / 160.f;
        float var  = aloadf(&ws[ZW_S3BQ + tid]) / 160.f - mean*mean;
        float s5 = g21[tid]*rsqrtf(var+EPS), t5v = b21[tid] - mean*s5;
        float m = -1e30f;
        #pragma unroll
        for (int p = 0; p < 5; p++)
            m = fmaxf(m, fmaxf(fmaf(s5, acc5[p], t5v), 0.f));
        out[b*256 + tid] = m;
    }
}

extern "C" void kernel_launch(void* const* d_in, const int* in_sizes, int n_in,
                              void* d_out, int out_size, void* d_ws, size_t ws_size,
                              hipStream_t stream) {
    (void)in_sizes; (void)n_in; (void)out_size; (void)ws_size;
    const float* x   = (const float*)d_in[0];
    const float* w00 = (const float*)d_in[1];
    const float* g00 = (const float*)d_in[2];
    const float* b00 = (const float*)d_in[3];
    const float* w01 = (const float*)d_in[4];
    const float* g01 = (const float*)d_in[5];
    const float* b01 = (const float*)d_in[6];
    const float* w10 = (const float*)d_in[7];
    const float* g10 = (const float*)d_in[8];
    const float* b10 = (const float*)d_in[9];
    const float* w11 = (const float*)d_in[10];
    const float* g11 = (const float*)d_in[11];
    const float* b11 = (const float*)d_in[12];
    const float* w20 = (const float*)d_in[13];
    const float* g20 = (const float*)d_in[14];
    const float* b20 = (const float*)d_in[15];
    const float* w21 = (const float*)d_in[16];
    const float* g21 = (const float*)d_in[17];
    const float* b21 = (const float*)d_in[18];
    float* out = (float*)d_out;
    float* ws  = (float*)d_ws;

    hipMemsetAsync(ws, 0, ZW_N*sizeof(float), stream);
    mega<<<NB, 256, 0, stream>>>(x, w00,g00,b00, w01,g01,b01, w10,g10,b10,
                                 w11,g11,b11, w20,g20,b20, w21,g21,b21, ws, out);
}

// Round 7
// 240.483 us; speedup vs baseline: 1.0729x; 1.0729x over previous
//
#include <hip/hip_runtime.h>
#include <math.h>

#define BB 32
#define GG 15
#define KK 2048
#define NB 480               // B*G blocks; co-resident (launch_bounds(256,2) -> 512 slots)
#define N1F 983040.0f
#define EPS 1e-5f

typedef _Float16 half8 __attribute__((ext_vector_type(8)));
typedef float f32x4 __attribute__((ext_vector_type(4)));

// ---- ws offsets (elements). Cross-block rule (R3/R5-proven): write via atomic
// RMW (atomicExch), order via vmcnt(0) drain, signal via per-block flag (==1 vs
// 0xAA poison), read via agent-scope atomic loads. No memset needed.
#define WS_SRELP 0                   // [480][8] per-bg central 2nd moments (6 used)
#define WS_CENT  (WS_SRELP + NB*8)   // [480][4]
#define WS_MAXV  (WS_CENT  + NB*4)   // [480][64]
#define WS_MINV  (WS_MAXV  + NB*64)
#define WS_SM1   (WS_MINV  + NB*64)  // [480][64]
#define WS_SQ1   (WS_SM1   + NB*64)
#define WS_S2AS  (WS_SQ1   + NB*64)  // [64][128] slot=(b*2+ph)
#define WS_S2AQ  (WS_S2AS  + 64*128)
#define WS_S2BS  (WS_S2AQ  + 64*128)
#define WS_S2BQ  (WS_S2BS  + 64*128)
#define WS_S3AS  (WS_S2BQ  + 64*128) // [32][256]
#define WS_S3AQ  (WS_S3AS  + 32*256)
#define WS_S3BS  (WS_S3AQ  + 32*256)
#define WS_S3BQ  (WS_S3BS  + 32*256)
#define WS_FLAG1 (WS_S3BQ  + 32*256) // [480] int
#define WS_FLAG2 (WS_FLAG1 + NB)     // [480] int
#define WS_FLAG3 (WS_FLAG2 + NB)     // [4][32] int

// ---- LDS map (floats). 15560 floats = 62240 B -> 2 blocks/CU (124.5 KB/CU).
// head:  xls[6144]@0 | redM@6144 redN@6400 redS@6656 redQ@6912 | bcast[9]@7168
// tail:  f2s@0(1005) h2a@1008(1920) h2b@2928(1920) f3s@4848(655) h3a@5504(1280)
//        sA@6784 tA@6848 c2ls@6912(15) c3ls@6928(3) centls@6932(45) wbuf@6984(8576)
#define SMEMF 15560

__device__ const int SIDX[15] = {0,1,8, 2,4,6, 3,5,7, 9,11,13, 10,12,14};
__device__ const int INV[15]  = {0,1,3,6,4,7,5,8,2,9,12,10,13,11,14};

__device__ __forceinline__ float wave_sum(float v){
    for (int off = 32; off; off >>= 1) v += __shfl_down(v, off, 64);
    return v;
}
__device__ __forceinline__ float aloadf(const float* p){
    return __hip_atomic_load(p, __ATOMIC_RELAXED, __HIP_MEMORY_SCOPE_AGENT);
}
__device__ __forceinline__ int aloadi(const int* p){
    return __hip_atomic_load(p, __ATOMIC_RELAXED, __HIP_MEMORY_SCOPE_AGENT);
}
__device__ __forceinline__ void fence_vm(){
    asm volatile("" ::: "memory");
    __builtin_amdgcn_s_waitcnt(0x0F70);   // vmcnt(0)
    asm volatile("" ::: "memory");
}
// flag barrier: threads [0,nthr) poll disjoint flag subsets, then block-sync.
template<int SLP>
__device__ __forceinline__ void spin_range(int* flags, int n, int nthr){
    int tid = threadIdx.x;
    if (tid < nthr) {
        for (int f = tid; f < n; f += nthr) {
            int guard = 0;
            while (aloadi(&flags[f]) != 1 && ++guard < 2000000)
                __builtin_amdgcn_s_sleep(SLP);
        }
    }
    __syncthreads();
}

__global__ void __launch_bounds__(256, 2) mega(
        const float* __restrict__ x,
        const float* __restrict__ w00, const float* __restrict__ g00, const float* __restrict__ b00,
        const float* __restrict__ w01, const float* __restrict__ g01, const float* __restrict__ b01,
        const float* __restrict__ w10, const float* __restrict__ g10, const float* __restrict__ b10,
        const float* __restrict__ w11, const float* __restrict__ g11, const float* __restrict__ b11,
        const float* __restrict__ w20, const float* __restrict__ g20, const float* __restrict__ b20,
        const float* __restrict__ w21, const float* __restrict__ g21, const float* __restrict__ b21,
        float* __restrict__ ws, float* __restrict__ out) {
    __shared__ __align__(16) float smemf[SMEMF];
    float* xls  = smemf;
    float* redM = smemf + 6144; float* redN = smemf + 6400;
    float* redS = smemf + 6656; float* redQ = smemf + 6912;
    float* bcast= smemf + 7168;
    int* wsi = (int*)ws;

    int bid = blockIdx.x, tid = threadIdx.x;
    int b_ = bid / GG, g_ = bid % GG;
    int wv = tid >> 6, lane = tid & 63, l15 = lane & 15, quad = lane >> 4;

    // ================= phase 1: x -> LDS; centroid + 3x3 moments ===============
    {
        const float4* xp4 = (const float4*)(x + (size_t)bid * KK * 3);
        float4* xls4 = (float4*)xls;
        #pragma unroll
        for (int i = 0; i < 6; i++) xls4[i*256 + tid] = xp4[i*256 + tid];
        __syncthreads();
        float m[9] = {0,0,0,0,0,0,0,0,0};
        float a[24];
        const float* bp = &xls[tid*24];
        #pragma unroll
        for (int i = 0; i < 6; i++)
            *reinterpret_cast<float4*>(&a[i*4]) = *reinterpret_cast<const float4*>(&bp[i*4]);
        #pragma unroll
        for (int p = 0; p < 8; p++) {
            float ax=a[p*3], ay=a[p*3+1], az=a[p*3+2];
            m[0]+=ax; m[1]+=ay; m[2]+=az;
            m[3]=fmaf(ax,ax,m[3]); m[4]=fmaf(ay,ay,m[4]); m[5]=fmaf(az,az,m[5]);
            m[6]=fmaf(ax,ay,m[6]); m[7]=fmaf(ax,az,m[7]); m[8]=fmaf(ay,az,m[8]);
        }
        #pragma unroll
        for (int q = 0; q < 9; q++) {
            float v = wave_sum(m[q]);
            if (lane == 0) redM[q*4 + wv] = v;
        }
        __syncthreads();
        if (tid == 0) {
            float t[9];
            #pragma unroll
            for (int q = 0; q < 9; q++) t[q] = redM[q*4]+redM[q*4+1]+redM[q*4+2]+redM[q*4+3];
            float c0 = t[0]/KK, c1 = t[1]/KK, c2 = t[2]/KK;
            bcast[0]=c0; bcast[1]=c1; bcast[2]=c2;
            out[8192 + b_*(67*GG) + 0*GG + g_] = c0;
            out[8192 + b_*(67*GG) + 1*GG + g_] = c1;
            out[8192 + b_*(67*GG) + 2*GG + g_] = c2;
            atomicExch(&ws[WS_CENT + bid*4 + 0], c0);
            atomicExch(&ws[WS_CENT + bid*4 + 1], c1);
            atomicExch(&ws[WS_CENT + bid*4 + 2], c2);
            atomicExch(&ws[WS_SRELP + bid*8 + 0], t[3] - KK*c0*c0);
            atomicExch(&ws[WS_SRELP + bid*8 + 1], t[4] - KK*c1*c1);
            atomicExch(&ws[WS_SRELP + bid*8 + 2], t[5] - KK*c2*c2);
            atomicExch(&ws[WS_SRELP + bid*8 + 3], t[6] - KK*c0*c1);
            atomicExch(&ws[WS_SRELP + bid*8 + 4], t[7] - KK*c0*c2);
            atomicExch(&ws[WS_SRELP + bid*8 + 5], t[8] - KK*c1*c2);
            fence_vm();
            atomicExch(&wsi[WS_FLAG1 + bid], 1);
        }
    }

    // hoisted weight prefetch (independent of barrier-1 data): A-frags + raw w00
    half8 afA[4], afB[4];
    #pragma unroll
    for (int t = 0; t < 4; t++)
        #pragma unroll
        for (int j = 0; j < 8; j++) {
            afA[t][j] = (_Float16)w01[(t*16 + l15)*64 + quad*8 + j];
            afB[t][j] = (_Float16)w01[(t*16 + l15)*64 + 32 + quad*8 + j];
        }

    spin_range<16>(&wsi[WS_FLAG1], NB, 64);   // grid barrier 1

    // ================= SREL gather: global 3x3 moment sums =====================
    {
        float sp[6] = {0,0,0,0,0,0};
        for (int r = tid; r < NB; r += 256) {
            #pragma unroll
            for (int q = 0; q < 6; q++) sp[q] += aloadf(&ws[WS_SRELP + r*8 + q]);
        }
        #pragma unroll
        for (int q = 0; q < 6; q++) {
            float v = wave_sum(sp[q]);
            if (lane == 0) redN[q*4 + wv] = v;
        }
        __syncthreads();
        if (tid == 0) {
            #pragma unroll
            for (int q = 0; q < 6; q++)
                bcast[3+q] = (redN[q*4]+redN[q*4+1]+redN[q*4+2]+redN[q*4+3]) / N1F;
        }
        __syncthreads();
    }
    float c0 = bcast[0], c1 = bcast[1], c2v = bcast[2];
    float S00=bcast[3], S11=bcast[4], S22=bcast[5], S01=bcast[6], S02=bcast[7], S12=bcast[8];

    // ================= phase 2: barrier-free MFMA over 2048 k ==================
    float wa0[8], wa1[8], wa2[8], ba[8], wb0[8], wb1[8], wb2[8], bb[8];
    #pragma unroll
    for (int j = 0; j < 8; j++) {
        int cA = quad*8 + j;
        float u0=w00[cA*3+0], u1=w00[cA*3+1], u2=w00[cA*3+2];
        float var = u0*u0*S00 + u1*u1*S11 + u2*u2*S22
                  + 2.f*(u0*u1*S01 + u0*u2*S02 + u1*u2*S12);
        float a1 = g00[cA]*rsqrtf(var + EPS);
        wa0[j]=a1*u0; wa1[j]=a1*u1; wa2[j]=a1*u2; ba[j]=b00[cA];
        int cB = cA + 32;
        float v0=w00[cB*3+0], v1=w00[cB*3+1], v2=w00[cB*3+2];
        float varB = v0*v0*S00 + v1*v1*S11 + v2*v2*S22
                   + 2.f*(v0*v1*S01 + v0*v2*S02 + v1*v2*S12);
        float a1B = g00[cB]*rsqrtf(varB + EPS);
        wb0[j]=a1B*v0; wb1[j]=a1B*v1; wb2[j]=a1B*v2; bb[j]=b00[cB];
    }
    float mx[16], mn[16], sm[16], sq[16];
    #pragma unroll
    for (int s = 0; s < 16; s++) { mx[s]=-1e30f; mn[s]=1e30f; sm[s]=0.f; sq[s]=0.f; }

    for (int it = 0; it < 32; it++) {
        int k = it*64 + wv*16 + l15;
        float r0 = xls[k*3+0]-c0, r1 = xls[k*3+1]-c1, r2 = xls[k*3+2]-c2v;
        half8 bf0, bf1;
        #pragma unroll
        for (int j = 0; j < 8; j++) {
            float pA = fmaf(wa0[j],r0, fmaf(wa1[j],r1, fmaf(wa2[j],r2, ba[j])));
            bf0[j] = (_Float16)fmaxf(pA, 0.f);
            float pB = fmaf(wb0[j],r0, fmaf(wb1[j],r1, fmaf(wb2[j],r2, bb[j])));
            bf1[j] = (_Float16)fmaxf(pB, 0.f);
        }
        #pragma unroll
        for (int t = 0; t < 4; t++) {
            f32x4 acc = {0.f,0.f,0.f,0.f};
            acc = __builtin_amdgcn_mfma_f32_16x16x32_f16(afA[t], bf0, acc, 0, 0, 0);
            acc = __builtin_amdgcn_mfma_f32_16x16x32_f16(afB[t], bf1, acc, 0, 0, 0);
            #pragma unroll
            for (int r = 0; r < 4; r++) {
                float h = acc[r];  // o = t*16 + quad*4 + r
                int s = t*4 + r;
                mx[s]=fmaxf(mx[s],h); mn[s]=fminf(mn[s],h);
                sm[s]+=h;             sq[s]=fmaf(h,h,sq[s]);
            }
        }
    }
    #pragma unroll
    for (int m = 1; m < 16; m <<= 1) {
        #pragma unroll
        for (int s = 0; s < 16; s++) {
            mx[s] = fmaxf(mx[s], __shfl_xor(mx[s], m, 64));
            mn[s] = fminf(mn[s], __shfl_xor(mn[s], m, 64));
            sm[s] += __shfl_xor(sm[s], m, 64);
            sq[s] += __shfl_xor(sq[s], m, 64);
        }
    }
    __syncthreads();
    if (l15 == 0) {
        #pragma unroll
        for (int t = 0; t < 4; t++)
            #pragma unroll
            for (int r = 0; r < 4; r++) {
                int o = t*16 + quad*4 + r;
                redM[wv*64+o]=mx[t*4+r]; redN[wv*64+o]=mn[t*4+r];
                redS[wv*64+o]=sm[t*4+r]; redQ[wv*64+o]=sq[t*4+r];
            }
    }
    __syncthreads();
    if (tid < 64) {
        float M=-1e30f, N=1e30f, S=0.f, Q=0.f;
        #pragma unroll
        for (int w = 0; w < 4; w++) {
            M = fmaxf(M, redM[w*64+tid]); N = fminf(N, redN[w*64+tid]);
            S += redS[w*64+tid];          Q += redQ[w*64+tid];
        }
        atomicExch(&ws[WS_MAXV + bid*64 + tid], M);
        atomicExch(&ws[WS_MINV + bid*64 + tid], N);
        atomicExch(&ws[WS_SM1  + bid*64 + tid], S);
        atomicExch(&ws[WS_SQ1  + bid*64 + tid], Q);
        fence_vm();
        if (tid == 0) atomicExch(&wsi[WS_FLAG2 + bid], 1);
    }

    if (bid >= BB) return;          // 448 blocks done; 32 tail blocks continue

    // ================= tail: stages 2+3, one block per batch b=bid =============
    spin_range<16>(&wsi[WS_FLAG2], NB, 64);   // grid barrier 2

    float* f2s = smemf;        float* h2a = smemf + 1008;
    float* h2b = smemf + 2928; float* f3s = smemf + 4848;
    float* h3a = smemf + 5504;
    float* sA  = smemf + 6784; float* tA  = smemf + 6848;
    float* c2ls= smemf + 6912; float* c3ls= smemf + 6928;
    float* centls = smemf + 6932;   // [15][3]
    float* wbuf = smemf + 6984;     // 8576-float staged weight tile
    int b = bid;

    // ---- phase 0: BN1 stats gather; centroids; c2/c3; lf1; feats2 ----
    {
        int o = tid & 63, qr = tid >> 6;
        float SM=0.f, SQ=0.f;
        for (int r = qr*120; r < qr*120 + 120; r++) {
            SM += aloadf(&ws[WS_SM1 + r*64 + o]);
            SQ += aloadf(&ws[WS_SQ1 + r*64 + o]);
        }
        redS[tid] = SM; redQ[tid] = SQ;   // head red arrays double as scratch here? no:
        __syncthreads();
        // NOTE: redS/redQ live at 6656/6912 which overlap tA/c2ls region boundaries
        // -> reduce immediately into sA/tA before any tail-area writes below.
        if (tid < 64) {
            float SMt=0.f, SQt=0.f;
            #pragma unroll
            for (int w = 0; w < 4; w++) { SMt += redS[w*64+tid]; SQt += redQ[w*64+tid]; }
            float mean = SMt / N1F;
            float var  = SQt / N1F - mean*mean;
            float s1 = g01[tid]*rsqrtf(var + EPS);
            sA[tid] = s1; tA[tid] = b01[tid] - mean*s1;
        } else if (tid < 109) {
            int t2 = tid - 64, g = t2/3, i = t2%3;
            centls[g*3+i] = aloadf(&ws[WS_CENT + (b*GG + g)*4 + i]);
        }
        __syncthreads();
        if (tid < 15) {
            int s = tid/3, i = tid%3;
            float acc = 0.f;
            for (int j = 0; j < 3; j++) acc += centls[SIDX[s*3+j]*3 + i];
            c2ls[tid] = acc * (1.f/3.f);
        }
        __syncthreads();
        if (tid < 3) {
            float a = 0.f;
            for (int s = 0; s < 5; s++) a += c2ls[s*3+tid];
            c3ls[tid] = a * 0.2f;
        }
        if (tid < 45) {
            int p = tid/3, i = tid%3;
            f2s[p*67 + i] = centls[SIDX[p]*3 + i] - c2ls[(p/3)*3 + i];
        }
        for (int idx = tid; idx < 960; idx += 256) {
            int g = idx >> 6, o2 = idx & 63, bg2 = b*GG + g;
            float s1 = sA[o2], t1 = tA[o2];
            float mxv = aloadf(&ws[WS_MAXV + bg2*64 + o2]);
            float mnv = aloadf(&ws[WS_MINV + bg2*64 + o2]);
            float val = fmaxf(fmaf(s1, (s1 >= 0.f) ? mxv : mnv, t1), 0.f);
            out[8192 + b*(67*GG) + (3+o2)*GG + g] = val;
            f2s[INV[g]*67 + 3 + o2] = val;
        }
        __syncthreads();
    }

    int o = tid & 127, ph = tid >> 7;

    // ---- phase A: stage w10 -> LDS; h2a = w10 @ f2 + slotted stats ----
    {
        for (int idx = tid; idx < 128*67; idx += 256) wbuf[idx] = w10[idx];
        __syncthreads();
        float accp[8] = {0,0,0,0,0,0,0,0};
        for (int c = 0; c < 67; c++) {
            float wv_ = wbuf[o*67 + c];       // stride 67 -> 2-way banks, free
            #pragma unroll
            for (int pi = 0; pi < 8; pi++) {
                int p = ph + 2*pi;
                if (p < 15) accp[pi] = fmaf(wv_, f2s[p*67+c], accp[pi]);
            }
        }
        float smv=0.f, sqv=0.f;
        #pragma unroll
        for (int pi = 0; pi < 8; pi++) {
            int p = ph + 2*pi;
            if (p < 15) { float a=accp[pi]; h2a[p*128+o]=a; smv+=a; sqv=fmaf(a,a,sqv); }
        }
        atomicExch(&ws[WS_S2AS + (b*2+ph)*128 + o], smv);
        atomicExch(&ws[WS_S2AQ + (b*2+ph)*128 + o], sqv);
        fence_vm();
        __syncthreads();
        if (tid == 0) atomicExch(&wsi[WS_FLAG3 + 0*32 + b], 1);
    }
    spin_range<2>(&wsi[WS_FLAG3 + 0*32], 32, 32);

    // ---- phase B: BN2a; h2b = w11 @ v (2 staged i-tiles of 64) + stats ----
    {
        float SM=0.f, SQ=0.f;
        for (int s = 0; s < 64; s++) {
            SM += aloadf(&ws[WS_S2AS + s*128 + o]);
            SQ += aloadf(&ws[WS_S2AQ + s*128 + o]);
        }
        float mean = SM/480.f, var = SQ/480.f - mean*mean;
        float s2 = g10[o]*rsqrtf(var+EPS), t2v = b10[o] - mean*s2;
        for (int p = ph; p < 15; p += 2)
            h2a[p*128+o] = fmaxf(fmaf(s2, h2a[p*128+o], t2v), 0.f);
        float accp[8] = {0,0,0,0,0,0,0,0};
        for (int ch = 0; ch < 2; ch++) {
            int i0 = ch*64;
            __syncthreads();
            for (int idx = tid; idx < 128*64; idx += 256) {
                int r = idx >> 6, j = idx & 63;
                wbuf[r*65 + j] = w11[r*128 + i0 + j];   // pad 65: conflict-free rows
            }
            __syncthreads();
            for (int j = 0; j < 64; j++) {
                float wv_ = wbuf[o*65 + j];
                #pragma unroll
                for (int pi = 0; pi < 8; pi++) {
                    int p = ph + 2*pi;
                    if (p < 15) accp[pi] = fmaf(wv_, h2a[p*128 + i0 + j], accp[pi]);
                }
            }
        }
        float smv=0.f, sqv=0.f;
        #pragma unroll
        for (int pi = 0; pi < 8; pi++) {
            int p = ph + 2*pi;
            if (p < 15) { float a=accp[pi]; h2b[p*128+o]=a; smv+=a; sqv=fmaf(a,a,sqv); }
        }
        atomicExch(&ws[WS_S2BS + (b*2+ph)*128 + o], smv);
        atomicExch(&ws[WS_S2BQ + (b*2+ph)*128 + o], sqv);
        fence_vm();
        __syncthreads();
        if (tid == 0) atomicExch(&wsi[WS_FLAG3 + 1*32 + b], 1);
    }
    spin_range<2>(&wsi[WS_FLAG3 + 1*32], 32, 32);

    // ---- phase C: lf2/feats3; h3a = w20 @ f3 (4 staged c-tiles) + stats ----
    {
        float SM=0.f, SQ=0.f;
        for (int s = 0; s < 64; s++) {
            SM += aloadf(&ws[WS_S2BS + s*128 + o]);
            SQ += aloadf(&ws[WS_S2BQ + s*128 + o]);
        }
        float mean = SM/480.f, var = SQ/480.f - mean*mean;
        float s3 = g11[o]*rsqrtf(var+EPS), t3v = b11[o] - mean*s3;
        if (ph == 0) {
            for (int s5 = 0; s5 < 5; s5++) {
                float m = -1e30f;
                #pragma unroll
                for (int j = 0; j < 3; j++)
                    m = fmaxf(m, fmaxf(fmaf(s3, h2b[(s5*3+j)*128+o], t3v), 0.f));
                f3s[s5*131 + 3 + o] = m;
            }
        }
        if (tid < 15) f3s[(tid/3)*131 + tid%3] = c2ls[tid] - c3ls[tid%3];
        float acc5[5] = {0,0,0,0,0};
        const int c0s[4] = {0,33,66,99}, cws[4] = {33,33,33,32};
        for (int ch = 0; ch < 4; ch++) {
            int cc0 = c0s[ch], CW = cws[ch];
            __syncthreads();
            for (int idx = tid; idx < 256*CW; idx += 256) {
                int r = idx / CW, j = idx - r*CW;
                wbuf[r*33 + j] = w20[r*131 + cc0 + j];
            }
            __syncthreads();
            for (int j = 0; j < CW; j++) {
                float wv_ = wbuf[tid*33 + j];    // stride 33 -> conflict-free
                #pragma unroll
                for (int p = 0; p < 5; p++)
                    acc5[p] = fmaf(wv_, f3s[p*131 + cc0 + j], acc5[p]);
            }
        }
        float smv=0.f, sqv=0.f;
        #pragma unroll
        for (int p = 0; p < 5; p++) { float a=acc5[p]; h3a[p*256+tid]=a; smv+=a; sqv=fmaf(a,a,sqv); }
        atomicExch(&ws[WS_S3AS + b*256 + tid], smv);
        atomicExch(&ws[WS_S3AQ + b*256 + tid], sqv);
        fence_vm();
        __syncthreads();
        if (tid == 0) atomicExch(&wsi[WS_FLAG3 + 2*32 + b], 1);
    }
    spin_range<2>(&wsi[WS_FLAG3 + 2*32], 32, 32);

    // ---- phase D: BN3a; h3b (registers) = w21 @ v (8 staged i-tiles) + stats ----
    float acc5[5] = {0,0,0,0,0};
    {
        float SM=0.f, SQ=0.f;
        for (int s = 0; s < 32; s++) {
            SM += aloadf(&ws[WS_S3AS + s*256 + tid]);
            SQ += aloadf(&ws[WS_S3AQ + s*256 + tid]);
        }
        float mean = SM/160.f, var = SQ/160.f - mean*mean;
        float s4 = g20[tid]*rsqrtf(var+EPS), t4v = b20[tid] - mean*s4;
        #pragma unroll
        for (int p = 0; p < 5; p++)
            h3a[p*256+tid] = fmaxf(fmaf(s4, h3a[p*256+tid], t4v), 0.f);
        for (int ch = 0; ch < 8; ch++) {
            int i0 = ch*32;
            __syncthreads();
            for (int idx = tid; idx < 256*32; idx += 256) {
                int r = idx >> 5, j = idx & 31;
                wbuf[r*33 + j] = w21[r*256 + i0 + j];
            }
            __syncthreads();
            for (int j = 0; j < 32; j++) {
                float wv_ = wbuf[tid*33 + j];
                #pragma unroll
                for (int p = 0; p < 5; p++)
                    acc5[p] = fmaf(wv_, h3a[p*256 + i0 + j], acc5[p]);
            }
        }
        float smv=0.f, sqv=0.f;
        #pragma unroll
        for (int p = 0; p < 5; p++) { smv += acc5[p]; sqv = fmaf(acc5[p], acc5[p], sqv); }
        atomicExch(&ws[WS_S3BS + b*256 + tid], smv);
        atomicExch(&ws[WS_S3BQ + b*256 + tid], sqv);
        fence_vm();
        __syncthreads();
        if (tid == 0) atomicExch(&wsi[WS_FLAG3 + 3*32 + b], 1);
    }
    spin_range<2>(&wsi[WS_FLAG3 + 3*32], 32, 32);

    // ---- phase E: gf = max_p relu(BN(h3b)) ----
    {
        float SM=0.f, SQ=0.f;
        for (int s = 0; s < 32; s++) {
            SM += aloadf(&ws[WS_S3BS + s*256 + tid]);
            SQ += aloadf(&ws[WS_S3BQ + s*256 + tid]);
        }
        float mean = SM/160.f, var = SQ/160.f - mean*mean;
        float s5 = g21[tid]*rsqrtf(var+EPS), t5v = b21[tid] - mean*s5;
        float m = -1e30f;
        #pragma unroll
        for (int p = 0; p < 5; p++)
            m = fmaxf(m, fmaxf(fmaf(s5, acc5[p], t5v), 0.f));
        out[b*256 + tid] = m;
    }
}

extern "C" void kernel_launch(void* const* d_in, const int* in_sizes, int n_in,
                              void* d_out, int out_size, void* d_ws, size_t ws_size,
                              hipStream_t stream) {
    (void)in_sizes; (void)n_in; (void)out_size; (void)ws_size;
    const float* x   = (const float*)d_in[0];
    const float* w00 = (const float*)d_in[1];
    const float* g00 = (const float*)d_in[2];
    const float* b00 = (const float*)d_in[3];
    const float* w01 = (const float*)d_in[4];
    const float* g01 = (const float*)d_in[5];
    const float* b01 = (const float*)d_in[6];
    const float* w10 = (const float*)d_in[7];
    const float* g10 = (const float*)d_in[8];
    const float* b10 = (const float*)d_in[9];
    const float* w11 = (const float*)d_in[10];
    const float* g11 = (const float*)d_in[11];
    const float* b11 = (const float*)d_in[12];
    const float* w20 = (const float*)d_in[13];
    const float* g20 = (const float*)d_in[14];
    const float* b20 = (const float*)d_in[15];
    const float* w21 = (const float*)d_in[16];
    const float* g21 = (const float*)d_in[17];
    const float* b21 = (const float*)d_in[18];
    float* out = (float*)d_out;
    float* ws  = (float*)d_ws;

    mega<<<NB, 256, 0, stream>>>(x, w00,g00,b00, w01,g01,b01, w10,g10,b10,
                                 w11,g11,b11, w20,g20,b20, w21,g21,b21, ws, out);
}

// Round 8
// 227.937 us; speedup vs baseline: 1.1320x; 1.0550x over previous
//
#include <hip/hip_runtime.h>
#include <math.h>

#define BB 32
#define GG 15
#define KK 2048
#define NB 480               // B*G blocks; co-resident (launch_bounds(256,2) -> 512 slots)
#define N1F 983040.0f
#define EPS 1e-5f

typedef _Float16 half8 __attribute__((ext_vector_type(8)));
typedef float f32x4 __attribute__((ext_vector_type(4)));

// ---- ws float offsets. Cross-block rule (R3/R5-proven): write via atomic RMW
// (atomicExch/atomicAdd), order via vmcnt(0) drain, signal via per-block flag
// (==1 vs 0xAA poison), read via agent-scope atomic loads.
#define WS_SRELP 0                    // [480][8] per-bg central 2nd moments
#define WS_CENT  (WS_SRELP + NB*8)    // [480][4]
#define WS_H2B   (WS_CENT + NB*4)     // [480][128] stage2 layer2 pre-BN
#define WS_H3B   (WS_H2B + NB*128)    // [160][256] stage3 layer2 pre-BN
#define ZW_BASE  (WS_H3B + 160*256)   // 1664 floats, zeroed by blocks 0..6 pre-bar1
#define ZW_BN1S  (ZW_BASE + 0)
#define ZW_BN1Q  (ZW_BASE + 64)
#define ZW_S2AS  (ZW_BASE + 128)
#define ZW_S2AQ  (ZW_BASE + 256)
#define ZW_S2BS  (ZW_BASE + 384)
#define ZW_S2BQ  (ZW_BASE + 512)
#define ZW_S3AS  (ZW_BASE + 640)
#define ZW_S3AQ  (ZW_BASE + 896)
#define ZW_S3BS  (ZW_BASE + 1152)
#define ZW_S3BQ  (ZW_BASE + 1408)
#define ZW_LEN   1664
#define WS_FLAG  (ZW_BASE + ZW_LEN)   // int view: 6 arrays of 480

// ---- LDS (floats): 7936 = 31744 B -> 2 blocks/CU.
// xls[6144]@0 (head; aliased as weight-tile buffer wls in tail)
// redM@6144 redN@6400 redS@6656 redQ@6912 (head combine; redM reused as tail partials)
// bcast@7168(16) c2ls@7184(16) c3ls@7200(4) f2ls@7204(68)
// vA@7272(128) f3ls@7400(132) h3ls@7532(256)  -> end 7788
#define SMEMF 7936

__device__ const int SIDX[15] = {0,1,8, 2,4,6, 3,5,7, 9,11,13, 10,12,14};
__device__ const int INV[15]  = {0,1,3,6,4,7,5,8,2,9,12,10,13,11,14};

__device__ __forceinline__ float wave_sum(float v){
    for (int off = 32; off; off >>= 1) v += __shfl_down(v, off, 64);
    return v;
}
__device__ __forceinline__ float aloadf(const float* p){
    return __hip_atomic_load(p, __ATOMIC_RELAXED, __HIP_MEMORY_SCOPE_AGENT);
}
__device__ __forceinline__ int aloadi(const int* p){
    return __hip_atomic_load(p, __ATOMIC_RELAXED, __HIP_MEMORY_SCOPE_AGENT);
}
__device__ __forceinline__ void fence_vm(){
    asm volatile("" ::: "memory");
    __builtin_amdgcn_s_waitcnt(0x0F70);   // vmcnt(0)
    asm volatile("" ::: "memory");
}
template<int SLP>
__device__ __forceinline__ void spin_range(int* flags, int n, int nthr){
    int tid = threadIdx.x;
    if (tid < nthr) {
        for (int f = tid; f < n; f += nthr) {
            int guard = 0;
            while (aloadi(&flags[f]) != 1 && ++guard < 2000000)
                __builtin_amdgcn_s_sleep(SLP);
        }
    }
    __syncthreads();
}

__global__ void __launch_bounds__(256, 2) mega(
        const float* __restrict__ x,
        const float* __restrict__ w00, const float* __restrict__ g00, const float* __restrict__ b00,
        const float* __restrict__ w01, const float* __restrict__ g01, const float* __restrict__ b01,
        const float* __restrict__ w10, const float* __restrict__ g10, const float* __restrict__ b10,
        const float* __restrict__ w11, const float* __restrict__ g11, const float* __restrict__ b11,
        const float* __restrict__ w20, const float* __restrict__ g20, const float* __restrict__ b20,
        const float* __restrict__ w21, const float* __restrict__ g21, const float* __restrict__ b21,
        float* __restrict__ ws, float* __restrict__ out) {
    __shared__ __align__(16) float smemf[SMEMF];
    float* xls  = smemf;                 // aliased as wls in tail
    float* wls  = smemf;
    float* redM = smemf + 6144; float* redN = smemf + 6400;
    float* redS = smemf + 6656; float* redQ = smemf + 6912;
    float* bcast= smemf + 7168;
    float* c2ls = smemf + 7184; float* c3ls = smemf + 7200;
    float* f2ls = smemf + 7204;
    float* vA   = smemf + 7272;
    float* f3ls = smemf + 7400;
    float* h3ls = smemf + 7532;
    int* wsi = (int*)ws;
    int* flag1 = wsi + WS_FLAG + 0*NB;
    int* flag2 = wsi + WS_FLAG + 1*NB;
    int* flag3 = wsi + WS_FLAG + 2*NB;
    int* flag4 = wsi + WS_FLAG + 3*NB;
    int* flag5 = wsi + WS_FLAG + 4*NB;
    int* flag6 = wsi + WS_FLAG + 5*NB;

    int bid = blockIdx.x, tid = threadIdx.x;
    int b_ = bid / GG, g_ = bid % GG;
    int wv = tid >> 6, lane = tid & 63, l15 = lane & 15, quad = lane >> 4;

    // ---- stats zeroing (blocks 0..6) BEFORE any loads; ordered before flag1 ----
    if (bid < 7) {
        int idx = bid*256 + tid;
        if (idx < ZW_LEN) atomicExch(&ws[ZW_BASE + idx], 0.f);
        fence_vm();
    }

    // ================= phase 1: x -> LDS; centroid + 3x3 moments ===============
    {
        const float4* xp4 = (const float4*)(x + (size_t)bid * KK * 3);
        float4* xls4 = (float4*)xls;
        #pragma unroll
        for (int i = 0; i < 6; i++) xls4[i*256 + tid] = xp4[i*256 + tid];
        __syncthreads();
        float m[9] = {0,0,0,0,0,0,0,0,0};
        float a[24];
        const float* bp = &xls[tid*24];
        #pragma unroll
        for (int i = 0; i < 6; i++)
            *reinterpret_cast<float4*>(&a[i*4]) = *reinterpret_cast<const float4*>(&bp[i*4]);
        #pragma unroll
        for (int p = 0; p < 8; p++) {
            float ax=a[p*3], ay=a[p*3+1], az=a[p*3+2];
            m[0]+=ax; m[1]+=ay; m[2]+=az;
            m[3]=fmaf(ax,ax,m[3]); m[4]=fmaf(ay,ay,m[4]); m[5]=fmaf(az,az,m[5]);
            m[6]=fmaf(ax,ay,m[6]); m[7]=fmaf(ax,az,m[7]); m[8]=fmaf(ay,az,m[8]);
        }
        #pragma unroll
        for (int q = 0; q < 9; q++) {
            float v = wave_sum(m[q]);
            if (lane == 0) redM[q*4 + wv] = v;
        }
        __syncthreads();
        if (tid == 0) {
            float t[9];
            #pragma unroll
            for (int q = 0; q < 9; q++) t[q] = redM[q*4]+redM[q*4+1]+redM[q*4+2]+redM[q*4+3];
            float c0 = t[0]/KK, c1 = t[1]/KK, c2 = t[2]/KK;
            bcast[0]=c0; bcast[1]=c1; bcast[2]=c2;
            out[8192 + b_*(67*GG) + 0*GG + g_] = c0;
            out[8192 + b_*(67*GG) + 1*GG + g_] = c1;
            out[8192 + b_*(67*GG) + 2*GG + g_] = c2;
            atomicExch(&ws[WS_CENT + bid*4 + 0], c0);
            atomicExch(&ws[WS_CENT + bid*4 + 1], c1);
            atomicExch(&ws[WS_CENT + bid*4 + 2], c2);
            atomicExch(&ws[WS_SRELP + bid*8 + 0], t[3] - KK*c0*c0);
            atomicExch(&ws[WS_SRELP + bid*8 + 1], t[4] - KK*c1*c1);
            atomicExch(&ws[WS_SRELP + bid*8 + 2], t[5] - KK*c2*c2);
            atomicExch(&ws[WS_SRELP + bid*8 + 3], t[6] - KK*c0*c1);
            atomicExch(&ws[WS_SRELP + bid*8 + 4], t[7] - KK*c0*c2);
            atomicExch(&ws[WS_SRELP + bid*8 + 5], t[8] - KK*c1*c2);
            fence_vm();
            atomicExch(&flag1[bid], 1);
        }
    }

    // hoisted A-frag prefetch (independent of barrier-1 data)
    half8 afA[4], afB[4];
    #pragma unroll
    for (int t = 0; t < 4; t++)
        #pragma unroll
        for (int j = 0; j < 8; j++) {
            afA[t][j] = (_Float16)w01[(t*16 + l15)*64 + quad*8 + j];
            afB[t][j] = (_Float16)w01[(t*16 + l15)*64 + 32 + quad*8 + j];
        }

    spin_range<16>(flag1, NB, 240);   // grid barrier 1

    // ---- SREL gather + per-b c2/c3 (centroids valid after bar1) ----
    {
        float sp[6] = {0,0,0,0,0,0};
        for (int r = tid; r < NB; r += 256) {
            #pragma unroll
            for (int q = 0; q < 6; q++) sp[q] += aloadf(&ws[WS_SRELP + r*8 + q]);
        }
        #pragma unroll
        for (int q = 0; q < 6; q++) {
            float v = wave_sum(sp[q]);
            if (lane == 0) redN[q*4 + wv] = v;
        }
        if (tid < 15) {  // c2ls for this block's b_
            int s = tid/3, i = tid%3;
            float acc = 0.f;
            #pragma unroll
            for (int j = 0; j < 3; j++)
                acc += aloadf(&ws[WS_CENT + (b_*GG + SIDX[s*3+j])*4 + i]);
            c2ls[tid] = acc * (1.f/3.f);
        }
        __syncthreads();
        if (tid == 0) {
            #pragma unroll
            for (int q = 0; q < 6; q++)
                bcast[3+q] = (redN[q*4]+redN[q*4+1]+redN[q*4+2]+redN[q*4+3]) / N1F;
        }
        if (tid < 3) {
            float a = 0.f;
            for (int s = 0; s < 5; s++) a += c2ls[s*3+tid];
            c3ls[tid] = a * 0.2f;
        }
        __syncthreads();
    }
    float c0 = bcast[0], c1 = bcast[1], c2v = bcast[2];
    float S00=bcast[3], S11=bcast[4], S22=bcast[5], S01=bcast[6], S02=bcast[7], S12=bcast[8];

    // ================= phase 2: barrier-free MFMA over 2048 k ==================
    float wa0[8], wa1[8], wa2[8], ba[8], wb0[8], wb1[8], wb2[8], bb[8];
    #pragma unroll
    for (int j = 0; j < 8; j++) {
        int cA = quad*8 + j;
        float u0=w00[cA*3+0], u1=w00[cA*3+1], u2=w00[cA*3+2];
        float var = u0*u0*S00 + u1*u1*S11 + u2*u2*S22
                  + 2.f*(u0*u1*S01 + u0*u2*S02 + u1*u2*S12);
        float a1 = g00[cA]*rsqrtf(var + EPS);
        wa0[j]=a1*u0; wa1[j]=a1*u1; wa2[j]=a1*u2; ba[j]=b00[cA];
        int cB = cA + 32;
        float v0=w00[cB*3+0], v1=w00[cB*3+1], v2=w00[cB*3+2];
        float varB = v0*v0*S00 + v1*v1*S11 + v2*v2*S22
                   + 2.f*(v0*v1*S01 + v0*v2*S02 + v1*v2*S12);
        float a1B = g00[cB]*rsqrtf(varB + EPS);
        wb0[j]=a1B*v0; wb1[j]=a1B*v1; wb2[j]=a1B*v2; bb[j]=b00[cB];
    }
    float mx[16], mn[16], sm[16], sq[16];
    #pragma unroll
    for (int s = 0; s < 16; s++) { mx[s]=-1e30f; mn[s]=1e30f; sm[s]=0.f; sq[s]=0.f; }

    for (int it = 0; it < 32; it++) {
        int k = it*64 + wv*16 + l15;
        float r0 = xls[k*3+0]-c0, r1 = xls[k*3+1]-c1, r2 = xls[k*3+2]-c2v;
        half8 bf0, bf1;
        #pragma unroll
        for (int j = 0; j < 8; j++) {
            float pA = fmaf(wa0[j],r0, fmaf(wa1[j],r1, fmaf(wa2[j],r2, ba[j])));
            bf0[j] = (_Float16)fmaxf(pA, 0.f);
            float pB = fmaf(wb0[j],r0, fmaf(wb1[j],r1, fmaf(wb2[j],r2, bb[j])));
            bf1[j] = (_Float16)fmaxf(pB, 0.f);
        }
        #pragma unroll
        for (int t = 0; t < 4; t++) {
            f32x4 acc = {0.f,0.f,0.f,0.f};
            acc = __builtin_amdgcn_mfma_f32_16x16x32_f16(afA[t], bf0, acc, 0, 0, 0);
            acc = __builtin_amdgcn_mfma_f32_16x16x32_f16(afB[t], bf1, acc, 0, 0, 0);
            #pragma unroll
            for (int r = 0; r < 4; r++) {
                float h = acc[r];  // o = t*16 + quad*4 + r
                int s = t*4 + r;
                mx[s]=fmaxf(mx[s],h); mn[s]=fminf(mn[s],h);
                sm[s]+=h;             sq[s]=fmaf(h,h,sq[s]);
            }
        }
    }
    #pragma unroll
    for (int m = 1; m < 16; m <<= 1) {
        #pragma unroll
        for (int s = 0; s < 16; s++) {
            mx[s] = fmaxf(mx[s], __shfl_xor(mx[s], m, 64));
            mn[s] = fminf(mn[s], __shfl_xor(mn[s], m, 64));
            sm[s] += __shfl_xor(sm[s], m, 64);
            sq[s] += __shfl_xor(sq[s], m, 64);
        }
    }
    __syncthreads();   // xls dead after this point
    if (l15 == 0) {
        #pragma unroll
        for (int t = 0; t < 4; t++)
            #pragma unroll
            for (int r = 0; r < 4; r++) {
                int o = t*16 + quad*4 + r;
                redM[wv*64+o]=mx[t*4+r]; redN[wv*64+o]=mn[t*4+r];
                redS[wv*64+o]=sm[t*4+r]; redQ[wv*64+o]=sq[t*4+r];
            }
    }
    __syncthreads();
    float Mreg = -1e30f, Nreg = 1e30f;      // per-(tid<64) own-bg max/min of h2
    if (tid < 64) {
        float S=0.f, Q=0.f;
        #pragma unroll
        for (int w = 0; w < 4; w++) {
            Mreg = fmaxf(Mreg, redM[w*64+tid]); Nreg = fminf(Nreg, redN[w*64+tid]);
            S += redS[w*64+tid];               Q += redQ[w*64+tid];
        }
        atomicAdd(&ws[ZW_BN1S + tid], S);
        atomicAdd(&ws[ZW_BN1Q + tid], Q);
        fence_vm();
    }
    __syncthreads();
    if (tid == 0) atomicExch(&flag2[bid], 1);

    spin_range<16>(flag2, NB, 240);   // grid barrier 2 — ALL 480 blocks continue

    int p_ = INV[g_];

    // ---- T0: f2 column for THIS (b,g): lf1 from own M/N, rel from own centroid ----
    if (tid < 64) {
        float SM = aloadf(&ws[ZW_BN1S + tid]);
        float SQ = aloadf(&ws[ZW_BN1Q + tid]);
        float mean = SM / N1F;
        float var  = SQ / N1F - mean*mean;
        float s1 = g01[tid]*rsqrtf(var + EPS);
        float t1 = b01[tid] - mean*s1;
        float val = fmaxf(fmaf(s1, (s1 >= 0.f) ? Mreg : Nreg, t1), 0.f);
        f2ls[3+tid] = val;
        out[8192 + b_*(67*GG) + (3+tid)*GG + g_] = val;
    } else if (tid < 67) {
        int i = tid - 64;
        f2ls[i] = bcast[i] - c2ls[(p_/3)*3 + i];
    }
    __syncthreads();

    // ---- phase A: h2a = w10 @ f2 (in-LDS), stats atomicAdd ----
    if (tid < 128) {
        float h = 0.f;
        #pragma unroll 1
        for (int c = 0; c < 67; c++) h = fmaf(w10[tid*67+c], f2ls[c], h);
        vA[tid] = h;
        atomicAdd(&ws[ZW_S2AS + tid], h);
        atomicAdd(&ws[ZW_S2AQ + tid], h*h);
        fence_vm();
    }
    __syncthreads();
    if (tid == 0) atomicExch(&flag3[bid], 1);
    spin_range<4>(flag3, NB, 240);

    // ---- phase B: BN2a; h2b = w11 @ v (staged LDS tiles, split over ph) ----
    {
        int o = tid & 127, ph = tid >> 7;
        float mean = aloadf(&ws[ZW_S2AS + o]) / 480.f;
        float var  = aloadf(&ws[ZW_S2AQ + o]) / 480.f - mean*mean;
        float s2 = g10[o]*rsqrtf(var+EPS), t2 = b10[o] - mean*s2;
        if (tid < 128) vA[tid] = fmaxf(fmaf(s2, vA[tid], t2), 0.f);
        float hacc = 0.f;
        for (int ch = 0; ch < 4; ch++) {
            __syncthreads();
            for (int idx = tid; idx < 128*32; idx += 256) {
                int r = idx >> 5, j = idx & 31;
                wls[r*33 + j] = w11[r*128 + ch*32 + j];
            }
            __syncthreads();
            if ((ch >> 1) == ph) {
                #pragma unroll
                for (int j = 0; j < 32; j++)
                    hacc = fmaf(wls[o*33+j], vA[ch*32+j], hacc);
            }
        }
        __syncthreads();
        redM[tid] = hacc;
        __syncthreads();
        if (tid < 128) {
            float h = redM[tid] + redM[tid+128];
            atomicExch(&ws[WS_H2B + (b_*GG + p_)*128 + tid], h);
            atomicAdd(&ws[ZW_S2BS + tid], h);
            atomicAdd(&ws[ZW_S2BQ + tid], h*h);
            fence_vm();
        }
        __syncthreads();
        if (tid == 0) atomicExch(&flag4[bid], 1);
    }
    spin_range<4>(flag4, NB, 240);

    // ---- phase C (160 blocks, g_<5): lf2 + feats3 + h3a = w20 @ f3 ----
    if (g_ < 5) {
        int s5 = g_;
        if (tid < 128) {
            float mean = aloadf(&ws[ZW_S2BS + tid]) / 480.f;
            float var  = aloadf(&ws[ZW_S2BQ + tid]) / 480.f - mean*mean;
            float s3 = g11[tid]*rsqrtf(var+EPS), t3 = b11[tid] - mean*s3;
            float m = -1e30f;
            #pragma unroll
            for (int j = 0; j < 3; j++) {
                float hv = aloadf(&ws[WS_H2B + (b_*GG + s5*3 + j)*128 + tid]);
                m = fmaxf(m, fmaxf(fmaf(s3, hv, t3), 0.f));
            }
            f3ls[3+tid] = m;
        } else if (tid < 131) {
            int i = tid - 128;
            f3ls[i] = c2ls[s5*3+i] - c3ls[i];
        }
        float hacc = 0.f;
        for (int ch = 0; ch < 9; ch++) {
            int cc0 = ch*16, w = (ch == 8) ? 3 : 16;
            __syncthreads();
            for (int idx = tid; idx < 256*w; idx += 256) {
                int r = idx / w, j = idx - r*w;
                wls[r*17 + j] = w20[r*131 + cc0 + j];
            }
            __syncthreads();
            for (int j = 0; j < w; j++)
                hacc = fmaf(wls[tid*17+j], f3ls[cc0+j], hacc);
        }
        h3ls[tid] = hacc;
        atomicAdd(&ws[ZW_S3AS + tid], hacc);
        atomicAdd(&ws[ZW_S3AQ + tid], hacc*hacc);
        fence_vm();
    }
    __syncthreads();
    if (tid == 0) atomicExch(&flag5[bid], 1);
    spin_range<4>(flag5, NB, 240);

    // ---- phase D (160 blocks): BN3a; h3b = w21 @ v (staged tiles) ----
    if (g_ < 5) {
        float mean = aloadf(&ws[ZW_S3AS + tid]) / 160.f;
        float var  = aloadf(&ws[ZW_S3AQ + tid]) / 160.f - mean*mean;
        float s4 = g20[tid]*rsqrtf(var+EPS), t4 = b20[tid] - mean*s4;
        h3ls[tid] = fmaxf(fmaf(s4, h3ls[tid], t4), 0.f);
        float hacc = 0.f;
        for (int ch = 0; ch < 16; ch++) {
            __syncthreads();
            for (int idx = tid; idx < 256*16; idx += 256) {
                int r = idx >> 4, j = idx & 15;
                wls[r*17 + j] = w21[r*256 + ch*16 + j];
            }
            __syncthreads();
            #pragma unroll
            for (int j = 0; j < 16; j++)
                hacc = fmaf(wls[tid*17+j], h3ls[ch*16+j], hacc);
        }
        atomicExch(&ws[WS_H3B + (b_*5 + g_)*256 + tid], hacc);
        atomicAdd(&ws[ZW_S3BS + tid], hacc);
        atomicAdd(&ws[ZW_S3BQ + tid], hacc*hacc);
        fence_vm();
    }
    __syncthreads();
    if (tid == 0) atomicExch(&flag6[bid], 1);
    spin_range<4>(flag6, NB, 240);

    // ---- phase E (32 blocks, g_==0): gf = max_s5 relu(BN(h3b)) ----
    if (g_ == 0) {
        float mean = aloadf(&ws[ZW_S3BS + tid]) / 160.f;
        float var  = aloadf(&ws[ZW_S3BQ + tid]) / 160.f - mean*mean;
        float s5c = g21[tid]*rsqrtf(var+EPS), t5 = b21[tid] - mean*s5c;
        float m = -1e30f;
        #pragma unroll
        for (int jj = 0; jj < 5; jj++) {
            float hv = aloadf(&ws[WS_H3B + (b_*5 + jj)*256 + tid]);
            m = fmaxf(m, fmaxf(fmaf(s5c, hv, t5), 0.f));
        }
        out[b_*256 + tid] = m;
    }
}

extern "C" void kernel_launch(void* const* d_in, const int* in_sizes, int n_in,
                              void* d_out, int out_size, void* d_ws, size_t ws_size,
                              hipStream_t stream) {
    (void)in_sizes; (void)n_in; (void)out_size; (void)ws_size;
    const float* x   = (const float*)d_in[0];
    const float* w00 = (const float*)d_in[1];
    const float* g00 = (const float*)d_in[2];
    const float* b00 = (const float*)d_in[3];
    const float* w01 = (const float*)d_in[4];
    const float* g01 = (const float*)d_in[5];
    const float* b01 = (const float*)d_in[6];
    const float* w10 = (const float*)d_in[7];
    const float* g10 = (const float*)d_in[8];
    const float* b10 = (const float*)d_in[9];
    const float* w11 = (const float*)d_in[10];
    const float* g11 = (const float*)d_in[11];
    const float* b11 = (const float*)d_in[12];
    const float* w20 = (const float*)d_in[13];
    const float* g20 = (const float*)d_in[14];
    const float* b20 = (const float*)d_in[15];
    const float* w21 = (const float*)d_in[16];
    const float* g21 = (const float*)d_in[17];
    const float* b21 = (const float*)d_in[18];
    float* out = (float*)d_out;
    float* ws  = (float*)d_ws;

    mega<<<NB, 256, 0, stream>>>(x, w00,g00,b00, w01,g01,b01, w10,g10,b10,
                                 w11,g11,b11, w20,g20,b20, w21,g21,b21, ws, out);
}

// Round 9
// 227.908 us; speedup vs baseline: 1.1321x; 1.0001x over previous
//
#include <hip/hip_runtime.h>
#include <math.h>

#define BB 32
#define GG 15
#define KK 2048
#define NB 480               // B*G blocks; co-resident (launch_bounds(256,2))
#define N1F 983040.0f
#define EPS 1e-5f

typedef _Float16 half8 __attribute__((ext_vector_type(8)));
typedef float f32x4 __attribute__((ext_vector_type(4)));

// ---- ws float offsets. Cross-block rule (R3/R5-proven): write via atomic RMW,
// order via vmcnt(0) drain, signal via write-once flag (==1 vs 0xAA poison),
// read via agent-scope atomic loads.
#define WS_SRELP 0                    // [480][8]
#define WS_CENT  (WS_SRELP + NB*8)    // [480][4]
#define WS_H2B   (WS_CENT + NB*4)     // [480][128]
#define WS_H3B   (WS_H2B + NB*128)    // [160][256]
#define ZW_BASE  (WS_H3B + 160*256)   // zeroed by block 0 behind init flag
#define ZW_BN1S  (ZW_BASE + 0)
#define ZW_BN1Q  (ZW_BASE + 64)
#define ZW_S2AS  (ZW_BASE + 128)
#define ZW_S2AQ  (ZW_BASE + 256)
#define ZW_S2BS  (ZW_BASE + 384)
#define ZW_S2BQ  (ZW_BASE + 512)
#define ZW_S3AS  (ZW_BASE + 640)
#define ZW_S3AQ  (ZW_BASE + 896)
#define ZW_S3BS  (ZW_BASE + 1152)
#define ZW_S3BQ  (ZW_BASE + 1408)
#define ZW_LEN   1664
// int offsets (same index space)
#define CNT_GRP  (ZW_BASE + ZW_LEN)   // [6][32] group counters
#define CNT_SUP  (CNT_GRP + 192)      // [6]
#define CNT_DONE (CNT_SUP + 6)        // [6]  (==1 semantics, no zero needed)
#define CNT_INIT (CNT_DONE + 6)       // 1    (==1 semantics)
#define CNT_ZLEN 198                  // GRP+SUP need zeroing

// ---- LDS (floats): 7936 = 31744 B -> 2+ blocks/CU ----
#define SMEMF 7936

__device__ const int SIDX[15] = {0,1,8, 2,4,6, 3,5,7, 9,11,13, 10,12,14};
__device__ const int INV[15]  = {0,1,3,6,4,7,5,8,2,9,12,10,13,11,14};

__device__ __forceinline__ float wave_sum(float v){
    for (int off = 32; off; off >>= 1) v += __shfl_down(v, off, 64);
    return v;
}
__device__ __forceinline__ float aloadf(const float* p){
    return __hip_atomic_load(p, __ATOMIC_RELAXED, __HIP_MEMORY_SCOPE_AGENT);
}
__device__ __forceinline__ int aloadi(const int* p){
    return __hip_atomic_load(p, __ATOMIC_RELAXED, __HIP_MEMORY_SCOPE_AGENT);
}
__device__ __forceinline__ void fence_vm(){
    asm volatile("" ::: "memory");
    __builtin_amdgcn_s_waitcnt(0x0F70);   // vmcnt(0)
    asm volatile("" ::: "memory");
}
// hierarchical grid barrier: 1 poller/block on a write-once done flag
template<int SLP>
__device__ __forceinline__ void gbar(int* wsi, int idx, int gidx, int ngrp){
    __syncthreads();
    if (threadIdx.x == 0) {
        fence_vm();
        if (atomicAdd(&wsi[CNT_GRP + idx*32 + gidx], 1) == 15) {
            if (atomicAdd(&wsi[CNT_SUP + idx], 1) == ngrp - 1)
                atomicExch(&wsi[CNT_DONE + idx], 1);
        }
        const int* done = &wsi[CNT_DONE + idx];
        int g = 0;
        while (aloadi(done) != 1 && ++g < 4000000) __builtin_amdgcn_s_sleep(SLP);
    }
    __syncthreads();
}

__global__ void __launch_bounds__(256, 2) mega(
        const float* __restrict__ x,
        const float* __restrict__ w00, const float* __restrict__ g00, const float* __restrict__ b00,
        const float* __restrict__ w01, const float* __restrict__ g01, const float* __restrict__ b01,
        const float* __restrict__ w10, const float* __restrict__ g10, const float* __restrict__ b10,
        const float* __restrict__ w11, const float* __restrict__ g11, const float* __restrict__ b11,
        const float* __restrict__ w20, const float* __restrict__ g20, const float* __restrict__ b20,
        const float* __restrict__ w21, const float* __restrict__ g21, const float* __restrict__ b21,
        float* __restrict__ ws, float* __restrict__ out) {
    __shared__ __align__(16) float smemf[SMEMF];
    float* xls  = smemf;
    float* redM = smemf + 6144; float* redN = smemf + 6400;
    float* redS = smemf + 6656; float* redQ = smemf + 6912;
    float* bcast= smemf + 7168;
    float* c2ls = smemf + 7184; float* c3ls = smemf + 7200;
    float* f2ls = smemf + 7204;
    float* vA   = smemf + 7272;
    float* f3ls = smemf + 7400;
    float* h3ls = smemf + 7532;
    int* wsi = (int*)ws;

    int bid = blockIdx.x, tid = threadIdx.x;
    int b_ = bid / GG, g_ = bid % GG;
    int wv = tid >> 6, lane = tid & 63, l15 = lane & 15, quad = lane >> 4;
    int gidx = bid >> 4;   // 30 groups of 16

    // ---- init: block 0 zeroes stats + barrier counters behind init flag ----
    if (bid == 0) {
        for (int i = tid; i < ZW_LEN; i += 256) atomicExch(&ws[ZW_BASE + i], 0.f);
        for (int i = tid; i < CNT_ZLEN; i += 256) atomicExch(&wsi[CNT_GRP + i], 0);
        fence_vm();                   // every wave drains its own exchs
        __syncthreads();
        if (tid == 0) atomicExch(&wsi[CNT_INIT], 1);
    }
    if (tid == 0) {
        int g = 0;
        while (aloadi(&wsi[CNT_INIT]) != 1 && ++g < 4000000)
            __builtin_amdgcn_s_sleep(8);
    }
    __syncthreads();

    // ================= phase 1: x -> LDS; centroid + 3x3 moments ===============
    {
        const float4* xp4 = (const float4*)(x + (size_t)bid * KK * 3);
        float4* xls4 = (float4*)xls;
        #pragma unroll
        for (int i = 0; i < 6; i++) xls4[i*256 + tid] = xp4[i*256 + tid];
        __syncthreads();
        float m[9] = {0,0,0,0,0,0,0,0,0};
        float a[24];
        const float* bp = &xls[tid*24];
        #pragma unroll
        for (int i = 0; i < 6; i++)
            *reinterpret_cast<float4*>(&a[i*4]) = *reinterpret_cast<const float4*>(&bp[i*4]);
        #pragma unroll
        for (int p = 0; p < 8; p++) {
            float ax=a[p*3], ay=a[p*3+1], az=a[p*3+2];
            m[0]+=ax; m[1]+=ay; m[2]+=az;
            m[3]=fmaf(ax,ax,m[3]); m[4]=fmaf(ay,ay,m[4]); m[5]=fmaf(az,az,m[5]);
            m[6]=fmaf(ax,ay,m[6]); m[7]=fmaf(ax,az,m[7]); m[8]=fmaf(ay,az,m[8]);
        }
        #pragma unroll
        for (int q = 0; q < 9; q++) {
            float v = wave_sum(m[q]);
            if (lane == 0) redM[q*4 + wv] = v;
        }
        __syncthreads();
        if (tid == 0) {
            float t[9];
            #pragma unroll
            for (int q = 0; q < 9; q++) t[q] = redM[q*4]+redM[q*4+1]+redM[q*4+2]+redM[q*4+3];
            float c0 = t[0]/KK, c1 = t[1]/KK, c2 = t[2]/KK;
            bcast[0]=c0; bcast[1]=c1; bcast[2]=c2;
            out[8192 + b_*(67*GG) + 0*GG + g_] = c0;
            out[8192 + b_*(67*GG) + 1*GG + g_] = c1;
            out[8192 + b_*(67*GG) + 2*GG + g_] = c2;
            atomicExch(&ws[WS_CENT + bid*4 + 0], c0);
            atomicExch(&ws[WS_CENT + bid*4 + 1], c1);
            atomicExch(&ws[WS_CENT + bid*4 + 2], c2);
            atomicExch(&ws[WS_SRELP + bid*8 + 0], t[3] - KK*c0*c0);
            atomicExch(&ws[WS_SRELP + bid*8 + 1], t[4] - KK*c1*c1);
            atomicExch(&ws[WS_SRELP + bid*8 + 2], t[5] - KK*c2*c2);
            atomicExch(&ws[WS_SRELP + bid*8 + 3], t[6] - KK*c0*c1);
            atomicExch(&ws[WS_SRELP + bid*8 + 4], t[7] - KK*c0*c2);
            atomicExch(&ws[WS_SRELP + bid*8 + 5], t[8] - KK*c1*c2);
        }
    }
    gbar<8>(wsi, 0, gidx, 30);        // barrier 1

    // ---- SREL gather + per-b c2/c3 ----
    {
        float sp[6] = {0,0,0,0,0,0};
        for (int r = tid; r < NB; r += 256) {
            #pragma unroll
            for (int q = 0; q < 6; q++) sp[q] += aloadf(&ws[WS_SRELP + r*8 + q]);
        }
        #pragma unroll
        for (int q = 0; q < 6; q++) {
            float v = wave_sum(sp[q]);
            if (lane == 0) redN[q*4 + wv] = v;
        }
        if (tid < 15) {
            int s = tid/3, i = tid%3;
            float acc = 0.f;
            #pragma unroll
            for (int j = 0; j < 3; j++)
                acc += aloadf(&ws[WS_CENT + (b_*GG + SIDX[s*3+j])*4 + i]);
            c2ls[tid] = acc * (1.f/3.f);
        }
        __syncthreads();
        if (tid == 0) {
            #pragma unroll
            for (int q = 0; q < 6; q++)
                bcast[3+q] = (redN[q*4]+redN[q*4+1]+redN[q*4+2]+redN[q*4+3]) / N1F;
        }
        if (tid < 3) {
            float a = 0.f;
            for (int s = 0; s < 5; s++) a += c2ls[s*3+tid];
            c3ls[tid] = a * 0.2f;
        }
        __syncthreads();
    }
    float c0 = bcast[0], c1 = bcast[1], c2v = bcast[2];
    float S00=bcast[3], S11=bcast[4], S22=bcast[5], S01=bcast[6], S02=bcast[7], S12=bcast[8];

    // ================= phase 2: barrier-free MFMA over 2048 k ==================
    half8 afA[4], afB[4];
    #pragma unroll
    for (int t = 0; t < 4; t++)
        #pragma unroll
        for (int j = 0; j < 8; j++) {
            afA[t][j] = (_Float16)w01[(t*16 + l15)*64 + quad*8 + j];
            afB[t][j] = (_Float16)w01[(t*16 + l15)*64 + 32 + quad*8 + j];
        }
    float wa0[8], wa1[8], wa2[8], ba[8], wb0[8], wb1[8], wb2[8], bb[8];
    #pragma unroll
    for (int j = 0; j < 8; j++) {
        int cA = quad*8 + j;
        float u0=w00[cA*3+0], u1=w00[cA*3+1], u2=w00[cA*3+2];
        float var = u0*u0*S00 + u1*u1*S11 + u2*u2*S22
                  + 2.f*(u0*u1*S01 + u0*u2*S02 + u1*u2*S12);
        float a1 = g00[cA]*rsqrtf(var + EPS);
        wa0[j]=a1*u0; wa1[j]=a1*u1; wa2[j]=a1*u2; ba[j]=b00[cA];
        int cB = cA + 32;
        float v0=w00[cB*3+0], v1=w00[cB*3+1], v2=w00[cB*3+2];
        float varB = v0*v0*S00 + v1*v1*S11 + v2*v2*S22
                   + 2.f*(v0*v1*S01 + v0*v2*S02 + v1*v2*S12);
        float a1B = g00[cB]*rsqrtf(varB + EPS);
        wb0[j]=a1B*v0; wb1[j]=a1B*v1; wb2[j]=a1B*v2; bb[j]=b00[cB];
    }
    float mx[16], mn[16], sm[16], sq[16];
    #pragma unroll
    for (int s = 0; s < 16; s++) { mx[s]=-1e30f; mn[s]=1e30f; sm[s]=0.f; sq[s]=0.f; }

    for (int it = 0; it < 32; it++) {
        int k = it*64 + wv*16 + l15;
        float r0 = xls[k*3+0]-c0, r1 = xls[k*3+1]-c1, r2 = xls[k*3+2]-c2v;
        half8 bf0, bf1;
        #pragma unroll
        for (int j = 0; j < 8; j++) {
            float pA = fmaf(wa0[j],r0, fmaf(wa1[j],r1, fmaf(wa2[j],r2, ba[j])));
            bf0[j] = (_Float16)fmaxf(pA, 0.f);
            float pB = fmaf(wb0[j],r0, fmaf(wb1[j],r1, fmaf(wb2[j],r2, bb[j])));
            bf1[j] = (_Float16)fmaxf(pB, 0.f);
        }
        #pragma unroll
        for (int t = 0; t < 4; t++) {
            f32x4 acc = {0.f,0.f,0.f,0.f};
            acc = __builtin_amdgcn_mfma_f32_16x16x32_f16(afA[t], bf0, acc, 0, 0, 0);
            acc = __builtin_amdgcn_mfma_f32_16x16x32_f16(afB[t], bf1, acc, 0, 0, 0);
            #pragma unroll
            for (int r = 0; r < 4; r++) {
                float h = acc[r];
                int s = t*4 + r;
                mx[s]=fmaxf(mx[s],h); mn[s]=fminf(mn[s],h);
                sm[s]+=h;             sq[s]=fmaf(h,h,sq[s]);
            }
        }
    }
    #pragma unroll
    for (int m = 1; m < 16; m <<= 1) {
        #pragma unroll
        for (int s = 0; s < 16; s++) {
            mx[s] = fmaxf(mx[s], __shfl_xor(mx[s], m, 64));
            mn[s] = fminf(mn[s], __shfl_xor(mn[s], m, 64));
            sm[s] += __shfl_xor(sm[s], m, 64);
            sq[s] += __shfl_xor(sq[s], m, 64);
        }
    }
    __syncthreads();
    if (l15 == 0) {
        #pragma unroll
        for (int t = 0; t < 4; t++)
            #pragma unroll
            for (int r = 0; r < 4; r++) {
                int o = t*16 + quad*4 + r;
                redM[wv*64+o]=mx[t*4+r]; redN[wv*64+o]=mn[t*4+r];
                redS[wv*64+o]=sm[t*4+r]; redQ[wv*64+o]=sq[t*4+r];
            }
    }
    __syncthreads();
    float Mreg = -1e30f, Nreg = 1e30f;
    if (tid < 64) {
        float S=0.f, Q=0.f;
        #pragma unroll
        for (int w = 0; w < 4; w++) {
            Mreg = fmaxf(Mreg, redM[w*64+tid]); Nreg = fminf(Nreg, redN[w*64+tid]);
            S += redS[w*64+tid];               Q += redQ[w*64+tid];
        }
        atomicAdd(&ws[ZW_BN1S + tid], S);
        atomicAdd(&ws[ZW_BN1Q + tid], Q);
    }
    gbar<8>(wsi, 1, gidx, 30);        // barrier 2

    int p_ = INV[g_];

    // ---- T0: this block's f2 column (lf1 from own M/N) ----
    if (tid < 64) {
        float SM = aloadf(&ws[ZW_BN1S + tid]);
        float SQ = aloadf(&ws[ZW_BN1Q + tid]);
        float mean = SM / N1F;
        float var  = SQ / N1F - mean*mean;
        float s1 = g01[tid]*rsqrtf(var + EPS);
        float t1 = b01[tid] - mean*s1;
        float val = fmaxf(fmaf(s1, (s1 >= 0.f) ? Mreg : Nreg, t1), 0.f);
        f2ls[3+tid] = val;
        out[8192 + b_*(67*GG) + (3+tid)*GG + g_] = val;
    } else if (tid < 67) {
        int i = tid - 64;
        f2ls[i] = bcast[i] - c2ls[(p_/3)*3 + i];
    }
    __syncthreads();

    // ---- phase A: h2a = w10 @ f2 (direct row reads) + stats ----
    if (tid < 128) {
        const float* wr = w10 + tid*67;
        float h = 0.f;
        #pragma unroll
        for (int c = 0; c < 67; c++) h = fmaf(wr[c], f2ls[c], h);
        vA[tid] = h;
        atomicAdd(&ws[ZW_S2AS + tid], h);
        atomicAdd(&ws[ZW_S2AQ + tid], h*h);
    }
    gbar<4>(wsi, 2, gidx, 30);        // barrier 3

    // ---- phase B: BN2a; h2b = w11 @ v (direct rows, split over halves) ----
    {
        int o = tid & 127, ph = tid >> 7;
        if (tid < 128) {
            float mean = aloadf(&ws[ZW_S2AS + o]) / 480.f;
            float var  = aloadf(&ws[ZW_S2AQ + o]) / 480.f - mean*mean;
            float s2 = g10[o]*rsqrtf(var+EPS), t2 = b10[o] - mean*s2;
            vA[o] = fmaxf(fmaf(s2, vA[o], t2), 0.f);
        }
        __syncthreads();
        const float* wr = w11 + o*128 + ph*64;
        const float* vv = vA + ph*64;
        float hacc = 0.f;
        #pragma unroll
        for (int j = 0; j < 64; j++) hacc = fmaf(wr[j], vv[j], hacc);
        redM[tid] = hacc;
        __syncthreads();
        if (tid < 128) {
            float h = redM[tid] + redM[tid+128];
            atomicExch(&ws[WS_H2B + (b_*GG + p_)*128 + tid], h);
            atomicAdd(&ws[ZW_S2BS + tid], h);
            atomicAdd(&ws[ZW_S2BQ + tid], h*h);
        }
    }
    gbar<4>(wsi, 3, gidx, 30);        // barrier 4

    if (g_ >= 5) return;              // 320 blocks done; 160 continue
    int gidx2 = (b_*5 + g_) >> 4;     // 10 groups of 16 among participants

    // ---- phase C: lf2 + feats3 + h3a = w20 @ f3 (direct rows) ----
    {
        int s5 = g_;
        if (tid < 128) {
            float mean = aloadf(&ws[ZW_S2BS + tid]) / 480.f;
            float var  = aloadf(&ws[ZW_S2BQ + tid]) / 480.f - mean*mean;
            float s3 = g11[tid]*rsqrtf(var+EPS), t3 = b11[tid] - mean*s3;
            float m = -1e30f;
            #pragma unroll
            for (int j = 0; j < 3; j++) {
                float hv = aloadf(&ws[WS_H2B + (b_*GG + s5*3 + j)*128 + tid]);
                m = fmaxf(m, fmaxf(fmaf(s3, hv, t3), 0.f));
            }
            f3ls[3+tid] = m;
        } else if (tid < 131) {
            int i = tid - 128;
            f3ls[i] = c2ls[s5*3+i] - c3ls[i];
        }
        __syncthreads();
        const float* wr = w20 + tid*131;
        float hacc = 0.f;
        #pragma unroll 4
        for (int c = 0; c < 131; c++) hacc = fmaf(wr[c], f3ls[c], hacc);
        h3ls[tid] = hacc;
        atomicAdd(&ws[ZW_S3AS + tid], hacc);
        atomicAdd(&ws[ZW_S3AQ + tid], hacc*hacc);
    }
    gbar<4>(wsi, 4, gidx2, 10);       // barrier 5 (160 blocks)

    // ---- phase D: BN3a; h3b = w21 @ v (direct rows) ----
    {
        float mean = aloadf(&ws[ZW_S3AS + tid]) / 160.f;
        float var  = aloadf(&ws[ZW_S3AQ + tid]) / 160.f - mean*mean;
        float s4 = g20[tid]*rsqrtf(var+EPS), t4 = b20[tid] - mean*s4;
        h3ls[tid] = fmaxf(fmaf(s4, h3ls[tid], t4), 0.f);
        __syncthreads();
        const float* wr = w21 + tid*256;
        float hacc = 0.f;
        #pragma unroll 4
        for (int i = 0; i < 256; i++) hacc = fmaf(wr[i], h3ls[i], hacc);
        atomicExch(&ws[WS_H3B + (b_*5 + g_)*256 + tid], hacc);
        atomicAdd(&ws[ZW_S3BS + tid], hacc);
        atomicAdd(&ws[ZW_S3BQ + tid], hacc*hacc);
    }
    gbar<4>(wsi, 5, gidx2, 10);       // barrier 6 (160 blocks)

    // ---- phase E (32 blocks, g_==0): gf = max_s5 relu(BN(h3b)) ----
    if (g_ == 0) {
        float mean = aloadf(&ws[ZW_S3BS + tid]) / 160.f;
        float var  = aloadf(&ws[ZW_S3BQ + tid]) / 160.f - mean*mean;
        float s5c = g21[tid]*rsqrtf(var+EPS), t5 = b21[tid] - mean*s5c;
        float m = -1e30f;
        #pragma unroll
        for (int jj = 0; jj < 5; jj++) {
            float hv = aloadf(&ws[WS_H3B + (b_*5 + jj)*256 + tid]);
            m = fmaxf(m, fmaxf(fmaf(s5c, hv, t5), 0.f));
        }
        out[b_*256 + tid] = m;
    }
}

extern "C" void kernel_launch(void* const* d_in, const int* in_sizes, int n_in,
                              void* d_out, int out_size, void* d_ws, size_t ws_size,
                              hipStream_t stream) {
    (void)in_sizes; (void)n_in; (void)out_size; (void)ws_size;
    const float* x   = (const float*)d_in[0];
    const float* w00 = (const float*)d_in[1];
    const float* g00 = (const float*)d_in[2];
    const float* b00 = (const float*)d_in[3];
    const float* w01 = (const float*)d_in[4];
    const float* g01 = (const float*)d_in[5];
    const float* b01 = (const float*)d_in[6];
    const float* w10 = (const float*)d_in[7];
    const float* g10 = (const float*)d_in[8];
    const float* b10 = (const float*)d_in[9];
    const float* w11 = (const float*)d_in[10];
    const float* g11 = (const float*)d_in[11];
    const float* b11 = (const float*)d_in[12];
    const float* w20 = (const float*)d_in[13];
    const float* g20 = (const float*)d_in[14];
    const float* b20 = (const float*)d_in[15];
    const float* w21 = (const float*)d_in[16];
    const float* g21 = (const float*)d_in[17];
    const float* b21 = (const float*)d_in[18];
    float* out = (float*)d_out;
    float* ws  = (float*)d_ws;

    mega<<<NB, 256, 0, stream>>>(x, w00,g00,b00, w01,g01,b01, w10,g10,b10,
                                 w11,g11,b11, w20,g20,b20, w21,g21,b21, ws, out);
}